// Round 15
// baseline (463.162 us; speedup 1.0000x reference)
//
#include <hip/hip_runtime.h>
#include <hip/hip_bf16.h>
#include <math.h>

// QuantumLLM fused pipeline, round 15: round-14 with the stage-A grid bug fixed.
// Round-14's failure (absmax 0.27) was a transcription bug: stage A grid was
// changed to dim3(4,128) -- its output is 16384x1024 so gx must be 8; half of
// gbuf stayed poisoned. The EPI-6 qk|v2T merge and single-pass-LN are unchanged.
// Algebra (rounds 1-4): qkv fold K3072->1024, 4/6 blocks; coll==1 const excitation;
// op_w folded into V so PV writes d_out directly.

#define TWO_PI_F 6.283185307179586f

typedef __attribute__((ext_vector_type(4))) float f32x4;
typedef __attribute__((ext_vector_type(8))) short bf16x8;
typedef __attribute__((ext_vector_type(4))) unsigned short u16x4;
typedef __hip_bfloat16 bf16;

__device__ __forceinline__ void gl_lds16(const void* g, void* l) {
  __builtin_amdgcn_global_load_lds((const __attribute__((address_space(1))) void*)g,
                                   (__attribute__((address_space(3))) void*)l, 16, 0, 0);
}
__device__ __forceinline__ unsigned short f2bf_bits(float f) {
  union { __hip_bfloat16 h; unsigned short u; } cv;
  cv.h = __float2bfloat16(f);
  return cv.u;
}
__device__ __forceinline__ float bf_bits2f(unsigned short b) {
  union { unsigned int u; float f; } cv;
  cv.u = ((unsigned int)b) << 16;
  return cv.f;
}

// ============ 128x128 GEMM, BK=64: C = epi(A * B^T * scale + bias) ============
// 4 waves (2x2), per-wave 64x64 = 4x4 frags x 2 k-steps of mfma_f32_16x16x32_bf16.
// 32 KB LDS single-buffered; 8-slot swizzle slot^=(row&7) both-sides (0 conflicts).
// useAB=false -> mfma(b,a): lane = C-row, regs = 4 consecutive C-cols (packed);
// useAB=true -> mfma(a,b): regs = 4 consecutive C-rows (v2T transposed store).
// EPI: 0 bias+bf16; 1 bias+gelu+bf16; 2 scale+bf16 (z batch); 3 PV batch full-K
//      (z=batch: bias + split fp32 direct to d_out); 5 PV split-K fallback;
//      6 merged qk|v2T (runtime per-block: bn>=1024 -> v2T).
template <int EPI, int ORD>
__global__ __launch_bounds__(256, 2) void gemm128(
    const bf16* __restrict__ A, const bf16* __restrict__ B, void* __restrict__ C,
    void* __restrict__ Cx, const float* __restrict__ bias, int K, int lda, int ldb, int ldc,
    float scale, long long zsa, long long zsb, long long zsc, float* __restrict__ P0,
    float* __restrict__ P1) {
  __shared__ __align__(16) bf16 smem[2 * 128 * 64];
  bf16* sA = smem;
  bf16* sB = smem + 128 * 64;
  const int tid = threadIdx.x;
  const int lane = tid & 63, wid = tid >> 6;
  const int wm = wid >> 1, wn = wid & 1;

  // XCD-bijective block swizzle (m204)
  const int gx = gridDim.x, gy = gridDim.y;
  int flat = blockIdx.x + gx * (blockIdx.y + gy * blockIdx.z);
  {
    const int nwg = gx * gy * gridDim.z;
    const int q = nwg >> 3, r = nwg & 7;
    const int x = flat & 7, loc = flat >> 3;
    flat = (x < r ? x * (q + 1) : r * (q + 1) + (x - r) * q) + loc;
  }
  const int bx = flat % gx;
  const int by = (flat / gx) % gy;
  const int bz = flat / (gx * gy);
  const int bm = by * 128, bn = bx * 128;

  const bf16 *Az, *Bz;
  if constexpr (EPI == 5) {
    const int b = bz & 1, c = bz >> 1;
    Az = A + (long long)b * zsa + c * 2048;
    Bz = B + (long long)b * zsb + c * 2048;
  } else {
    Az = A + (long long)bz * zsa;
    Bz = B + (long long)bz * zsb;
  }

  // operand order: compile-time except EPI 6 (block-uniform runtime)
  bool useAB;
  if constexpr (EPI == 6)
    useAB = (bn >= 1024);
  else
    useAB = (ORD == 0);

  f32x4 acc[4][4];
#pragma unroll
  for (int i = 0; i < 4; ++i)
#pragma unroll
    for (int j = 0; j < 4; ++j) acc[i][j] = (f32x4){0.f, 0.f, 0.f, 0.f};

  // staging constants: 4 granules per thread per matrix (row=c>>3, slot=c&7),
  // linear DMA dest, global elem offset pre-swizzled
  long long rowA[4], rowB[4];
#pragma unroll
  for (int t = 0; t < 4; ++t) {
    const int c = tid + 256 * t;
    const int r = c >> 3, s = c & 7;
    const int ga = ((s ^ (r & 7)) << 3);
    rowA[t] = (long long)(bm + r) * lda + ga;
    rowB[t] = (long long)(bn + r) * ldb + ga;
  }

  const int fr = lane & 15, ksl = lane >> 4;

  for (int k0 = 0; k0 < K; k0 += 64) {
#pragma unroll
    for (int t = 0; t < 4; ++t) gl_lds16(Az + rowA[t] + k0, &sA[(tid + 256 * t) * 8]);
#pragma unroll
    for (int t = 0; t < 4; ++t) gl_lds16(Bz + rowB[t] + k0, &sB[(tid + 256 * t) * 8]);
    __syncthreads();
    bf16x8 af[4][2], bfv[4][2];
#pragma unroll
    for (int i = 0; i < 4; ++i) {
      const int R = wm * 64 + i * 16 + fr;
#pragma unroll
      for (int kk = 0; kk < 2; ++kk) {
        const int s = (kk * 4 + ksl) ^ (R & 7);
        af[i][kk] = *(const bf16x8*)&sA[R * 64 + s * 8];
      }
    }
#pragma unroll
    for (int j = 0; j < 4; ++j) {
      const int R = wn * 64 + j * 16 + fr;
#pragma unroll
      for (int kk = 0; kk < 2; ++kk) {
        const int s = (kk * 4 + ksl) ^ (R & 7);
        bfv[j][kk] = *(const bf16x8*)&sB[R * 64 + s * 8];
      }
    }
    if (useAB) {
#pragma unroll
      for (int kk = 0; kk < 2; ++kk)
#pragma unroll
        for (int i = 0; i < 4; ++i)
#pragma unroll
          for (int j = 0; j < 4; ++j)
            acc[i][j] =
                __builtin_amdgcn_mfma_f32_16x16x32_bf16(af[i][kk], bfv[j][kk], acc[i][j], 0, 0, 0);
    } else {
#pragma unroll
      for (int kk = 0; kk < 2; ++kk)
#pragma unroll
        for (int i = 0; i < 4; ++i)
#pragma unroll
          for (int j = 0; j < 4; ++j)
            acc[i][j] =
                __builtin_amdgcn_mfma_f32_16x16x32_bf16(bfv[j][kk], af[i][kk], acc[i][j], 0, 0, 0);
    }
    __syncthreads();
  }

  // ---- epilogue ----
  if ((EPI == 6) && useAB) {
    // v2T: regs = 4 consecutive m-rows, lane fr = d-col. Round-trip through LDS
    // as [d_loc][8B-slot along m], slot XOR s^=(d&7)<<1, then coalesced 16B stores.
    bf16* st = smem;
#pragma unroll
    for (int i = 0; i < 4; ++i)
#pragma unroll
      for (int j = 0; j < 4; ++j) {
        const int m0 = wm * 64 + i * 16 + ksl * 4;
        const int dl = wn * 64 + j * 16 + fr;
        const float bv = bias[bn + dl];  // beff[1024 + d]
        u16x4 w;
#pragma unroll
        for (int r = 0; r < 4; ++r) w[r] = f2bf_bits(acc[i][j][r] * scale + bv);
        const int s = (m0 >> 2) ^ ((dl & 7) << 1);
        *(u16x4*)&st[dl * 128 + s * 4] = w;
      }
    __syncthreads();
    const int b = bm >> 12;
    const int mmb = bm & 4095;
    const int d0 = bn - 1024;
#pragma unroll
    for (int tt = 0; tt < 8; ++tt) {
      const int idx = tt * 256 + tid;
      const int dl = idx >> 4;
      const int q = idx & 15;
      const int s = (2 * q) ^ ((dl & 7) << 1);
      const bf16x8 vv = *(const bf16x8*)&st[dl * 128 + s * 4];
      *(bf16x8*)((unsigned short*)Cx +
                 ((long long)(b * 1024 + d0 + dl)) * 4096 + mmb + q * 8) = vv;
    }
  } else {
#pragma unroll
    for (int i = 0; i < 4; ++i)
#pragma unroll
      for (int j = 0; j < 4; ++j) {
        // packed layout: lane fr = C-row, regs = 4 consecutive C-cols
        const int row = bm + wm * 64 + i * 16 + fr;
        const int col0 = bn + wn * 64 + j * 16 + ksl * 4;
        f32x4 v = acc[i][j];
#pragma unroll
        for (int r = 0; r < 4; ++r) v[r] *= scale;
        if constexpr (EPI == 0 || EPI == 1 || EPI == 6) {
          if (bias) {
            const f32x4 bv = *(const f32x4*)&bias[col0];
            v += bv;
          }
        }
        if constexpr (EPI == 1) {
#pragma unroll
          for (int r = 0; r < 4; ++r) {
            const float t = v[r];
            float y = 0.7978845608028654f * (t + 0.044715f * t * t * t);
            y = fminf(fmaxf(y, -15.f), 15.f);
            const float e = __expf(2.f * y);
            v[r] = t * e / (1.f + e);
          }
        }
        if constexpr (EPI == 3) {
          const f32x4 bv = *(const f32x4*)&bias[col0];
          v += bv;
          float* dst = (col0 < 512) ? (float*)C : (float*)Cx;
          const long long rout = (long long)bz * 4096 + row;
          *(f32x4*)&dst[rout * 512 + (col0 & 511)] = v;
        } else if constexpr (EPI == 5) {
          const int b = bz & 1, c = bz >> 1;
          if (c == 0) {
            const f32x4 bv = *(const f32x4*)&bias[col0];
            v += bv;
            float* dst = (col0 < 512) ? (float*)C : (float*)Cx;
            const long long rout = zsc + (long long)b * 4096 + row;
            *(f32x4*)&dst[rout * 512 + (col0 & 511)] = v;
          } else {
            float* dst = b ? P1 : P0;
            *(f32x4*)&dst[(long long)row * 1024 + col0] = v;
          }
        } else if constexpr (EPI == 2) {
          bf16* cc = (bf16*)C + (long long)bz * zsc;
          u16x4 w;
#pragma unroll
          for (int r = 0; r < 4; ++r) w[r] = f2bf_bits(v[r]);
          *(u16x4*)&cc[(long long)row * ldc + col0] = w;
        } else {
          bf16* cc = (bf16*)C;
          u16x4 w;
#pragma unroll
          for (int r = 0; r < 4; ++r) w[r] = f2bf_bits(v[r]);
          *(u16x4*)&cc[(long long)row * ldc + col0] = w;
        }
      }
  }
  (void)ldc;
}

// ---------------- combine: out += partial (fallback path only) ----------------
__global__ __launch_bounds__(256) void combine_kernel(const float* __restrict__ p0,
                                                      const float* __restrict__ p1,
                                                      float* __restrict__ out0,
                                                      float* __restrict__ out1) {
  const int idx = blockIdx.x * 256 + threadIdx.x;
  const int b = idx >> 20;
  const int rem = idx & 1048575;
  const int row = rem >> 8;
  const int c4 = rem & 255;
  const float* p = b ? p1 : p0;
  const f32x4 v = *(const f32x4*)(p + (long long)row * 1024 + c4 * 4);
  float* dst = (c4 < 128) ? out0 : out1;
  const long long o = ((long long)(b * 4096 + row)) * 512 + (c4 & 127) * 4;
  f32x4 d = *(f32x4*)(dst + o);
  d += v;
  *(f32x4*)(dst + o) = d;
}

// ---------------- LayerNorm + phase ops (single-pass moments) ----------------
__global__ __launch_bounds__(256) void ln_phase_kernel(
    const bf16* __restrict__ g, bf16* __restrict__ u, const float* __restrict__ ln_g,
    const float* __restrict__ ln_b, const float* __restrict__ lcos,
    const float* __restrict__ lsin, const float* __restrict__ cost,
    const float* __restrict__ sint) {
  __shared__ float sg[1024];
  __shared__ float red[4], red2[4];
  const int tid = threadIdx.x;
  const int lane = tid & 63, wid = tid >> 6;
  const long long row = blockIdx.x;
  const bf16* gr = g + row * 1024;

  const u16x4 raw = *(const u16x4*)(gr + tid * 4);
  float lv[4];
  float lsum = 0.f, lsq = 0.f;
#pragma unroll
  for (int e = 0; e < 4; ++e) {
    lv[e] = bf_bits2f(raw[e]);
    lsum += lv[e];
    lsq += lv[e] * lv[e];
  }
  *(f32x4*)&sg[tid * 4] = *(f32x4*)lv;
#pragma unroll
  for (int off = 32; off > 0; off >>= 1) {
    lsum += __shfl_xor(lsum, off);
    lsq += __shfl_xor(lsq, off);
  }
  if (lane == 0) {
    red[wid] = lsum;
    red2[wid] = lsq;
  }
  __syncthreads();
  const float mu = (red[0] + red[1] + red[2] + red[3]) * (1.0f / 1024.0f);
  const float ex2 = (red2[0] + red2[1] + red2[2] + red2[3]) * (1.0f / 1024.0f);
  const float var = ex2 - mu * mu;
  const float rs = rsqrtf(var + 1e-5f);

#pragma unroll
  for (int kk = 0; kk < 2; ++kk) {
    const int p = tid + kk * 256;
    const float rp = (sg[p] - mu) * rs * ln_g[p] + ln_b[p];
    const float ip = (sg[p + 512] - mu) * rs * ln_g[p + 512] + ln_b[p + 512];
    const float ang = atan2f(ip + 1e-8f, rp + 1e-8f);
    int idx = (int)((ang / TWO_PI_F) * 1023.0f);
    idx = idx < 0 ? idx + 1024 : idx;
    float real = rp * cost[idx];
    float imag = ip * sint[idx];
    const float nrm = rsqrtf(real * real + imag * imag + 1e-8f) * 0.044194173824159216f;
    real *= nrm;
    imag *= nrm;
    const float amp = sqrtf(real * real + imag * imag + 1e-8f);
    const float coll = (amp < 0.1f) ? 1.0f : 0.0f;
    real += coll * lcos[p];
    imag += coll * lsin[p];
    const float n2 = rsqrtf(real * real + imag * imag + 1e-8f);
    u[row * 1024 + p] = __float2bfloat16(real * n2);
    u[row * 1024 + 512 + p] = __float2bfloat16(imag * n2);
  }
}

// ---------------- rowwise softmax, register-only (row = 4096) ----------------
__global__ __launch_bounds__(256) void softmax_kernel(bf16* __restrict__ s) {
  __shared__ float red[4];
  const int tid = threadIdx.x;
  const int lane = tid & 63, wid = tid >> 6;
  bf16* sr = s + (long long)blockIdx.x * 4096;
  f32x4 f[4];
  float mx = -3.0e38f;
#pragma unroll
  for (int k = 0; k < 4; ++k) {
    const u16x4 raw = *(const u16x4*)(sr + (k * 256 + tid) * 4);
#pragma unroll
    for (int e = 0; e < 4; ++e) {
      f[k][e] = bf_bits2f(raw[e]);
      mx = fmaxf(mx, f[k][e]);
    }
  }
#pragma unroll
  for (int off = 32; off > 0; off >>= 1) mx = fmaxf(mx, __shfl_xor(mx, off));
  if (lane == 0) red[wid] = mx;
  __syncthreads();
  mx = fmaxf(fmaxf(red[0], red[1]), fmaxf(red[2], red[3]));
  __syncthreads();
  float sum = 0.f;
#pragma unroll
  for (int k = 0; k < 4; ++k)
#pragma unroll
    for (int e = 0; e < 4; ++e) {
      f[k][e] = __expf(f[k][e] - mx);
      sum += f[k][e];
    }
#pragma unroll
  for (int off = 32; off > 0; off >>= 1) sum += __shfl_xor(sum, off);
  if (lane == 0) red[wid] = sum;
  __syncthreads();
  const float inv = 1.0f / (red[0] + red[1] + red[2] + red[3]);
#pragma unroll
  for (int k = 0; k < 4; ++k) {
    u16x4 w;
#pragma unroll
    for (int e = 0; e < 4; ++e) w[e] = f2bf_bits(f[k][e] * inv);
    *(u16x4*)(sr + (k * 256 + tid) * 4) = w;
  }
}

// ---------------- merged prep: folds + tables + all fp32->bf16 casts ----------------
__global__ __launch_bounds__(256) void fold_all(
    const float* __restrict__ w, const float* __restrict__ b,
    const float* __restrict__ op_w, const float* __restrict__ exc,
    const float* __restrict__ ft_w, const float* __restrict__ x, bf16* __restrict__ weff,
    bf16* __restrict__ wvT, float* __restrict__ beff, float* __restrict__ cost,
    float* __restrict__ sint, float* __restrict__ lcos, float* __restrict__ lsin,
    bf16* __restrict__ ftw_b, bf16* __restrict__ opw_b, bf16* __restrict__ x_b) {
  __shared__ float tile[32][33];
  __shared__ float red[4];
  const int blk = blockIdx.x;
  const int tid = threadIdx.x;
  if (blk < 4096) {
    const int i = blk * 256 + tid;
    const int o = i >> 10, j = i & 1023;
    const int so = (o < 512) ? o : o + 512;
    const float* wr = w + (long long)so * 3072;
    weff[i] = __float2bfloat16(wr[j] + wr[1024 + j] + wr[2048 + j]);
    if (j == 0) beff[o] = b[so];
  } else if (blk < 5120) {
    const int tb = blk - 4096;
    const int t0 = (tb & 31) * 32, j0 = (tb >> 5) * 32;
    const int tx = tid & 31, ty = tid >> 5;
#pragma unroll
    for (int k = 0; k < 4; ++k) {
      const int t = t0 + ty + k * 8;
      const float* wr = w + (long long)(2048 + t) * 3072 + j0 + tx;
      tile[ty + k * 8][tx] = wr[0] + wr[1024] + wr[2048];
    }
    __syncthreads();
#pragma unroll
    for (int k = 0; k < 4; ++k) {
      const int r = ty + k * 8;
      wvT[(long long)(j0 + r) * 1024 + t0 + tx] = __float2bfloat16(tile[tx][r]);
    }
  } else if (blk < 6144) {
    const int o = blk - 5120;
    const int lane = tid & 63, wid = tid >> 6;
    float s = 0.f;
#pragma unroll
    for (int k = 0; k < 4; ++k) {
      const int t = tid + k * 256;
      s += op_w[(long long)o * 1024 + t] * b[2048 + t];
    }
#pragma unroll
    for (int off = 32; off > 0; off >>= 1) s += __shfl_xor(s, off);
    if (lane == 0) red[wid] = s;
    __syncthreads();
    if (tid == 0) beff[1024 + o] = red[0] + red[1] + red[2] + red[3];
  } else if (blk == 6144) {
    const double step = 6.283185307179586 / 1023.0;
#pragma unroll
    for (int k = 0; k < 4; ++k) {
      const int i = tid + k * 256;
      const float a = (float)((double)i * step);
      cost[i] = cosf(a);
      sint[i] = sinf(a);
    }
#pragma unroll
    for (int k = 0; k < 2; ++k) {
      const int i = tid + k * 256;
      const float el = ((float)i / 511.0f) * TWO_PI_F;
      const float m = fmodf(el, TWO_PI_F);
      int li = (int)((m / TWO_PI_F) * 1024.0f);
      li = min(max(li, 0), 1023);
      const float a = (float)((double)li * step);
      lcos[i] = cosf(a) * exc[0];
      lsin[i] = sinf(a) * exc[0];
    }
  } else if (blk < 6657) {
    const long long q = (long long)(blk - 6145) * 256 + tid;
    const f32x4 f = *(const f32x4*)(ft_w + q * 4);
    u16x4 wv;
#pragma unroll
    for (int e = 0; e < 4; ++e) wv[e] = f2bf_bits(f[e]);
    *(u16x4*)((unsigned short*)ftw_b + q * 4) = wv;
  } else if (blk < 7681) {
    const long long q = (long long)(blk - 6657) * 256 + tid;
    const f32x4 f = *(const f32x4*)(op_w + q * 4);
    u16x4 wv;
#pragma unroll
    for (int e = 0; e < 4; ++e) wv[e] = f2bf_bits(f[e]);
    *(u16x4*)((unsigned short*)opw_b + q * 4) = wv;
  } else {
    const long long q0 = (long long)(blk - 7681) * 256 + tid;
#pragma unroll
    for (int t = 0; t < 4; ++t) {
      const long long q = q0 + (long long)t * 524288;
      const f32x4 f = *(const f32x4*)(x + q * 4);
      u16x4 wv;
#pragma unroll
      for (int e = 0; e < 4; ++e) wv[e] = f2bf_bits(f[e]);
      *(u16x4*)((unsigned short*)x_b + q * 4) = wv;
    }
  }
}

extern "C" void kernel_launch(void* const* d_in, const int* in_sizes, int n_in, void* d_out,
                              int out_size, void* d_ws, size_t ws_size, hipStream_t stream) {
  const float* x = (const float*)d_in[0];
  const float* ft_w = (const float*)d_in[1];
  const float* ft_b = (const float*)d_in[2];
  const float* ln_g = (const float*)d_in[3];
  const float* ln_b = (const float*)d_in[4];
  const float* exc = (const float*)d_in[5];
  const float* qkv_w = (const float*)d_in[6];
  const float* qkv_b = (const float*)d_in[7];
  const float* op_w = (const float*)d_in[8];
  const float* op_b = (const float*)d_in[9];

  char* ws = (char*)d_ws;
  const size_t MB = 1024ull * 1024ull;
  bf16* ftw_b = (bf16*)(ws + 0);                // 1 MB
  bf16* weff = (bf16*)(ws + 1 * MB);            // 4 MB (q,k rows 0:1024; W_v2 1024:2048)
  bf16* opw_b = (bf16*)(ws + 5 * MB);           // 2 MB
  bf16* wvT = (bf16*)(ws + 7 * MB);             // 2 MB
  float* beff = (float*)(ws + 9 * MB);          // 8 KB
  float* cost = (float*)(ws + 9 * MB + 8192);
  float* sint = (float*)(ws + 9 * MB + 12288);
  float* lcos = (float*)(ws + 9 * MB + 16384);
  float* lsin = (float*)(ws + 9 * MB + 18432);
  bf16* v2T = (bf16*)(ws + 10 * MB);            // 32 MB (4 x 1024 x 4096)
  bf16* qk = (bf16*)(ws + 42 * MB);             // 32 MB (16384 x [q|k])
  bf16* x_b = (bf16*)(ws + 74 * MB);            // 16 MB, dead after stage A
  bf16* gbuf = (bf16*)(ws + 90 * MB);           // 32 MB, dead after LN
  bf16* ubuf = (bf16*)(ws + 122 * MB);          // 32 MB, dead after qk/v2 GEMM
  bf16* sc = (bf16*)(ws + 74 * MB);             // scores: 128 MB (big) / 64 MB (pair)
  float* part0 = (float*)(ws + 138 * MB);       // 16 MB (fallback only)
  float* part1 = (float*)(ws + 154 * MB);       // 16 MB (fallback only)

  const bool big = ws_size >= 204 * MB;  // 4-batch sc fits (74 + 128 = 202 MB)

  fold_all<<<9729, 256, 0, stream>>>(qkv_w, qkv_b, op_w, exc, ft_w, x, weff, wvT, beff, cost,
                                     sint, lcos, lsin, ftw_b, opw_b, x_b);

  // W_v2 = op_w @ W_v -> weff rows 1024:2048
  gemm128<0, 1><<<dim3(8, 8), 256, 0, stream>>>(opw_b, wvT, weff + 1024 * 1024, nullptr,
                                                nullptr, 1024, 1024, 1024, 1024, 1.0f, 0, 0,
                                                0, nullptr, nullptr);
  // stage A: g = gelu(x @ ft_w^T + ft_b)   [N=1024 -> gx=8]
  gemm128<1, 1><<<dim3(8, 128), 256, 0, stream>>>(x_b, ftw_b, gbuf, nullptr, ft_b, 512, 512,
                                                  512, 1024, 1.0f, 0, 0, 0, nullptr, nullptr);
  // LN + phase -> u
  ln_phase_kernel<<<16384, 256, 0, stream>>>(gbuf, ubuf, ln_g, ln_b, lcos, lsin, cost, sint);
  // merged: cols 0:1024 -> qk (packed), cols 1024:2048 -> v2T (transposed)
  gemm128<6, 1><<<dim3(16, 128), 256, 0, stream>>>(ubuf, weff, qk, v2T, beff, 1024, 1024,
                                                   1024, 1024, 1.0f, 0, 0, 0, nullptr,
                                                   nullptr);

  float* out0 = (float*)d_out;
  float* out1 = out0 + 8388608LL;
  if (big) {
    // all 4 batches in one pass: S -> softmax -> out = P @ V2 + op_b (full K)
    gemm128<2, 1><<<dim3(32, 32, 4), 256, 0, stream>>>(
        qk, qk + 512, sc, nullptr, nullptr, 512, 1024, 1024, 4096, 0.04419417382415922f,
        4096LL * 1024, 4096LL * 1024, 4096LL * 4096, nullptr, nullptr);
    softmax_kernel<<<16384, 256, 0, stream>>>(sc);
    gemm128<3, 1><<<dim3(8, 32, 4), 256, 0, stream>>>(
        sc, v2T, out0, out1, op_b, 4096, 4096, 4096, 0, 1.0f, 4096LL * 4096, 1024LL * 4096,
        0, nullptr, nullptr);
  } else {
    for (int p = 0; p < 2; ++p) {
      const bf16* qbase = qk + (long long)(2 * p) * 4096 * 1024;
      gemm128<2, 1><<<dim3(32, 32, 2), 256, 0, stream>>>(
          qbase, qbase + 512, sc, nullptr, nullptr, 512, 1024, 1024, 4096,
          0.04419417382415922f, 4096LL * 1024, 4096LL * 1024, 4096LL * 4096, nullptr,
          nullptr);
      softmax_kernel<<<8192, 256, 0, stream>>>(sc);
      gemm128<5, 1><<<dim3(8, 32, 4), 256, 0, stream>>>(
          sc, v2T + (long long)(2 * p) * 1024 * 4096, out0, out1, op_b, 2048, 4096, 4096, 0,
          1.0f, 4096LL * 4096, 1024LL * 4096, (long long)(2 * p) * 4096, part0, part1);
      combine_kernel<<<8192, 256, 0, stream>>>(part0, part1,
                                               out0 + (long long)(2 * p) * 4096 * 512,
                                               out1 + (long long)(2 * p) * 4096 * 512);
    }
  }
  (void)in_sizes;
  (void)n_in;
  (void)out_size;
}

// Round 16
// 427.110 us; speedup vs baseline: 1.0844x; 1.0844x over previous
//
#include <hip/hip_runtime.h>
#include <hip/hip_bf16.h>
#include <math.h>

// QuantumLLM fused pipeline, round 16: revert the EPI-6 qk|v2T merge (round-15
// regression: runtime operand-order branch carried both MFMA orders + epilogues in
// one kernel, 74us -> 109us). Separate specialized dispatches restored (round-13
// structure); single-pass LN kept. PV z=4 full-K (1066 TF, 49% MfmaUtil = the
// BK=64 2-barrier engine's LDS-BW bound), scores 968 TF, conflicts 0.
// Algebra (rounds 1-4): qkv fold K3072->1024, 4/6 blocks; coll==1 const excitation;
// op_w folded into V so PV writes d_out directly.

#define TWO_PI_F 6.283185307179586f

typedef __attribute__((ext_vector_type(4))) float f32x4;
typedef __attribute__((ext_vector_type(8))) short bf16x8;
typedef __attribute__((ext_vector_type(4))) unsigned short u16x4;
typedef __hip_bfloat16 bf16;

__device__ __forceinline__ void gl_lds16(const void* g, void* l) {
  __builtin_amdgcn_global_load_lds((const __attribute__((address_space(1))) void*)g,
                                   (__attribute__((address_space(3))) void*)l, 16, 0, 0);
}
__device__ __forceinline__ unsigned short f2bf_bits(float f) {
  union { __hip_bfloat16 h; unsigned short u; } cv;
  cv.h = __float2bfloat16(f);
  return cv.u;
}
__device__ __forceinline__ float bf_bits2f(unsigned short b) {
  union { unsigned int u; float f; } cv;
  cv.u = ((unsigned int)b) << 16;
  return cv.f;
}

// ============ 128x128 GEMM, BK=64: C = epi(A * B^T * scale + bias) ============
// 4 waves (2x2), per-wave 64x64 = 4x4 frags x 2 k-steps of mfma_f32_16x16x32_bf16.
// 32 KB LDS single-buffered; 8-slot swizzle slot^=(row&7) both-sides (0 conflicts).
// ORD=1: mfma(b,a) -> lane = C-row, regs = 4 consecutive C-cols (packed stores).
// ORD=0: mfma(a,b) -> regs = 4 consecutive C-rows (for v2T transposed store).
// EPI: 0 bias+bf16; 1 bias+gelu+bf16; 2 scale+bf16 (z batch); 3 PV batch full-K
//      (z=batch: bias + split fp32 direct to d_out); 4 v2T transposed via LDS
//      round-trip (ORD=0); 5 PV split-K fallback (chunk0 direct, chunk1 partial).
template <int EPI, int ORD>
__global__ __launch_bounds__(256, 2) void gemm128(
    const bf16* __restrict__ A, const bf16* __restrict__ B, void* __restrict__ C,
    void* __restrict__ Cx, const float* __restrict__ bias, int K, int lda, int ldb, int ldc,
    float scale, long long zsa, long long zsb, long long zsc, float* __restrict__ P0,
    float* __restrict__ P1) {
  __shared__ __align__(16) bf16 smem[2 * 128 * 64];
  bf16* sA = smem;
  bf16* sB = smem + 128 * 64;
  const int tid = threadIdx.x;
  const int lane = tid & 63, wid = tid >> 6;
  const int wm = wid >> 1, wn = wid & 1;

  // XCD-bijective block swizzle (m204)
  const int gx = gridDim.x, gy = gridDim.y;
  int flat = blockIdx.x + gx * (blockIdx.y + gy * blockIdx.z);
  {
    const int nwg = gx * gy * gridDim.z;
    const int q = nwg >> 3, r = nwg & 7;
    const int x = flat & 7, loc = flat >> 3;
    flat = (x < r ? x * (q + 1) : r * (q + 1) + (x - r) * q) + loc;
  }
  const int bx = flat % gx;
  const int by = (flat / gx) % gy;
  const int bz = flat / (gx * gy);
  const int bm = by * 128, bn = bx * 128;

  const bf16 *Az, *Bz;
  if constexpr (EPI == 5) {
    const int b = bz & 1, c = bz >> 1;
    Az = A + (long long)b * zsa + c * 2048;
    Bz = B + (long long)b * zsb + c * 2048;
  } else {
    Az = A + (long long)bz * zsa;
    Bz = B + (long long)bz * zsb;
  }

  f32x4 acc[4][4];
#pragma unroll
  for (int i = 0; i < 4; ++i)
#pragma unroll
    for (int j = 0; j < 4; ++j) acc[i][j] = (f32x4){0.f, 0.f, 0.f, 0.f};

  // staging constants: 4 granules per thread per matrix (row=c>>3, slot=c&7),
  // linear DMA dest, global elem offset pre-swizzled
  long long rowA[4], rowB[4];
#pragma unroll
  for (int t = 0; t < 4; ++t) {
    const int c = tid + 256 * t;
    const int r = c >> 3, s = c & 7;
    const int ga = ((s ^ (r & 7)) << 3);
    rowA[t] = (long long)(bm + r) * lda + ga;
    rowB[t] = (long long)(bn + r) * ldb + ga;
  }

  const int fr = lane & 15, ksl = lane >> 4;

  for (int k0 = 0; k0 < K; k0 += 64) {
#pragma unroll
    for (int t = 0; t < 4; ++t) gl_lds16(Az + rowA[t] + k0, &sA[(tid + 256 * t) * 8]);
#pragma unroll
    for (int t = 0; t < 4; ++t) gl_lds16(Bz + rowB[t] + k0, &sB[(tid + 256 * t) * 8]);
    __syncthreads();
    bf16x8 af[4][2], bfv[4][2];
#pragma unroll
    for (int i = 0; i < 4; ++i) {
      const int R = wm * 64 + i * 16 + fr;
#pragma unroll
      for (int kk = 0; kk < 2; ++kk) {
        const int s = (kk * 4 + ksl) ^ (R & 7);
        af[i][kk] = *(const bf16x8*)&sA[R * 64 + s * 8];
      }
    }
#pragma unroll
    for (int j = 0; j < 4; ++j) {
      const int R = wn * 64 + j * 16 + fr;
#pragma unroll
      for (int kk = 0; kk < 2; ++kk) {
        const int s = (kk * 4 + ksl) ^ (R & 7);
        bfv[j][kk] = *(const bf16x8*)&sB[R * 64 + s * 8];
      }
    }
#pragma unroll
    for (int kk = 0; kk < 2; ++kk)
#pragma unroll
      for (int i = 0; i < 4; ++i)
#pragma unroll
        for (int j = 0; j < 4; ++j) {
          if constexpr (ORD == 0)
            acc[i][j] =
                __builtin_amdgcn_mfma_f32_16x16x32_bf16(af[i][kk], bfv[j][kk], acc[i][j], 0, 0, 0);
          else
            acc[i][j] =
                __builtin_amdgcn_mfma_f32_16x16x32_bf16(bfv[j][kk], af[i][kk], acc[i][j], 0, 0, 0);
        }
    __syncthreads();
  }

  // ---- epilogue ----
  if constexpr (EPI == 4) {
    // ORD==0: regs = 4 consecutive m-rows, lane fr = d-col. Round-trip through
    // LDS as [d_loc][8B-slot along m], slot XOR s^=(d&7)<<1 (bit0 untouched ->
    // 16B reads aligned), then coalesced 16B global stores.
    bf16* st = smem;  // 128 d x 32 slots x 8B = 32 KB (K-loop done, barrier'd)
#pragma unroll
    for (int i = 0; i < 4; ++i)
#pragma unroll
      for (int j = 0; j < 4; ++j) {
        const int m0 = wm * 64 + i * 16 + ksl * 4;  // local m, multiple of 4
        const int dl = wn * 64 + j * 16 + fr;       // local d
        const float bv = bias[bn + dl];             // beff2[bn + dl]
        u16x4 w;
#pragma unroll
        for (int r = 0; r < 4; ++r) w[r] = f2bf_bits(acc[i][j][r] * scale + bv);
        const int s = (m0 >> 2) ^ ((dl & 7) << 1);
        *(u16x4*)&st[dl * 128 + s * 4] = w;
      }
    __syncthreads();
    const int b = bm >> 12;
    const int mmb = bm & 4095;
#pragma unroll
    for (int tt = 0; tt < 8; ++tt) {
      const int idx = tt * 256 + tid;   // 0..2047
      const int dl = idx >> 4;          // 0..127
      const int q = idx & 15;           // 16B chunk of 8 m
      const int s = (2 * q) ^ ((dl & 7) << 1);
      const bf16x8 vv = *(const bf16x8*)&st[dl * 128 + s * 4];
      *(bf16x8*)((unsigned short*)Cx +
                 ((long long)(b * 1024 + bn + dl)) * 4096 + mmb + q * 8) = vv;
    }
  } else {
#pragma unroll
    for (int i = 0; i < 4; ++i)
#pragma unroll
      for (int j = 0; j < 4; ++j) {
        // ORD==1: lane fr = C-row, regs = 4 consecutive C-cols
        const int row = bm + wm * 64 + i * 16 + fr;
        const int col0 = bn + wn * 64 + j * 16 + ksl * 4;
        f32x4 v = acc[i][j];
#pragma unroll
        for (int r = 0; r < 4; ++r) v[r] *= scale;
        if constexpr (EPI == 0 || EPI == 1) {
          if (bias) {
            const f32x4 bv = *(const f32x4*)&bias[col0];
            v += bv;
          }
        }
        if constexpr (EPI == 1) {
#pragma unroll
          for (int r = 0; r < 4; ++r) {
            const float t = v[r];
            float y = 0.7978845608028654f * (t + 0.044715f * t * t * t);
            y = fminf(fmaxf(y, -15.f), 15.f);
            const float e = __expf(2.f * y);
            v[r] = t * e / (1.f + e);
          }
        }
        if constexpr (EPI == 3) {
          const f32x4 bv = *(const f32x4*)&bias[col0];
          v += bv;
          float* dst = (col0 < 512) ? (float*)C : (float*)Cx;
          const long long rout = (long long)bz * 4096 + row;
          *(f32x4*)&dst[rout * 512 + (col0 & 511)] = v;
        } else if constexpr (EPI == 5) {
          const int b = bz & 1, c = bz >> 1;
          if (c == 0) {
            const f32x4 bv = *(const f32x4*)&bias[col0];
            v += bv;
            float* dst = (col0 < 512) ? (float*)C : (float*)Cx;
            const long long rout = zsc + (long long)b * 4096 + row;
            *(f32x4*)&dst[rout * 512 + (col0 & 511)] = v;
          } else {
            float* dst = b ? P1 : P0;
            *(f32x4*)&dst[(long long)row * 1024 + col0] = v;
          }
        } else if constexpr (EPI == 2) {
          bf16* cc = (bf16*)C + (long long)bz * zsc;
          u16x4 w;
#pragma unroll
          for (int r = 0; r < 4; ++r) w[r] = f2bf_bits(v[r]);
          *(u16x4*)&cc[(long long)row * ldc + col0] = w;
        } else {
          bf16* cc = (bf16*)C;
          u16x4 w;
#pragma unroll
          for (int r = 0; r < 4; ++r) w[r] = f2bf_bits(v[r]);
          *(u16x4*)&cc[(long long)row * ldc + col0] = w;
        }
      }
  }
  (void)ldc;
}

// ---------------- combine: out += partial (fallback path only) ----------------
__global__ __launch_bounds__(256) void combine_kernel(const float* __restrict__ p0,
                                                      const float* __restrict__ p1,
                                                      float* __restrict__ out0,
                                                      float* __restrict__ out1) {
  const int idx = blockIdx.x * 256 + threadIdx.x;
  const int b = idx >> 20;
  const int rem = idx & 1048575;
  const int row = rem >> 8;
  const int c4 = rem & 255;
  const float* p = b ? p1 : p0;
  const f32x4 v = *(const f32x4*)(p + (long long)row * 1024 + c4 * 4);
  float* dst = (c4 < 128) ? out0 : out1;
  const long long o = ((long long)(b * 4096 + row)) * 512 + (c4 & 127) * 4;
  f32x4 d = *(f32x4*)(dst + o);
  d += v;
  *(f32x4*)(dst + o) = d;
}

// ---------------- LayerNorm + phase ops (single-pass moments) ----------------
__global__ __launch_bounds__(256) void ln_phase_kernel(
    const bf16* __restrict__ g, bf16* __restrict__ u, const float* __restrict__ ln_g,
    const float* __restrict__ ln_b, const float* __restrict__ lcos,
    const float* __restrict__ lsin, const float* __restrict__ cost,
    const float* __restrict__ sint) {
  __shared__ float sg[1024];
  __shared__ float red[4], red2[4];
  const int tid = threadIdx.x;
  const int lane = tid & 63, wid = tid >> 6;
  const long long row = blockIdx.x;
  const bf16* gr = g + row * 1024;

  const u16x4 raw = *(const u16x4*)(gr + tid * 4);
  float lv[4];
  float lsum = 0.f, lsq = 0.f;
#pragma unroll
  for (int e = 0; e < 4; ++e) {
    lv[e] = bf_bits2f(raw[e]);
    lsum += lv[e];
    lsq += lv[e] * lv[e];
  }
  *(f32x4*)&sg[tid * 4] = *(f32x4*)lv;
#pragma unroll
  for (int off = 32; off > 0; off >>= 1) {
    lsum += __shfl_xor(lsum, off);
    lsq += __shfl_xor(lsq, off);
  }
  if (lane == 0) {
    red[wid] = lsum;
    red2[wid] = lsq;
  }
  __syncthreads();
  const float mu = (red[0] + red[1] + red[2] + red[3]) * (1.0f / 1024.0f);
  const float ex2 = (red2[0] + red2[1] + red2[2] + red2[3]) * (1.0f / 1024.0f);
  const float var = ex2 - mu * mu;
  const float rs = rsqrtf(var + 1e-5f);

#pragma unroll
  for (int kk = 0; kk < 2; ++kk) {
    const int p = tid + kk * 256;
    const float rp = (sg[p] - mu) * rs * ln_g[p] + ln_b[p];
    const float ip = (sg[p + 512] - mu) * rs * ln_g[p + 512] + ln_b[p + 512];
    const float ang = atan2f(ip + 1e-8f, rp + 1e-8f);
    int idx = (int)((ang / TWO_PI_F) * 1023.0f);
    idx = idx < 0 ? idx + 1024 : idx;
    float real = rp * cost[idx];
    float imag = ip * sint[idx];
    const float nrm = rsqrtf(real * real + imag * imag + 1e-8f) * 0.044194173824159216f;
    real *= nrm;
    imag *= nrm;
    const float amp = sqrtf(real * real + imag * imag + 1e-8f);
    const float coll = (amp < 0.1f) ? 1.0f : 0.0f;
    real += coll * lcos[p];
    imag += coll * lsin[p];
    const float n2 = rsqrtf(real * real + imag * imag + 1e-8f);
    u[row * 1024 + p] = __float2bfloat16(real * n2);
    u[row * 1024 + 512 + p] = __float2bfloat16(imag * n2);
  }
}

// ---------------- rowwise softmax, register-only (row = 4096) ----------------
__global__ __launch_bounds__(256) void softmax_kernel(bf16* __restrict__ s) {
  __shared__ float red[4];
  const int tid = threadIdx.x;
  const int lane = tid & 63, wid = tid >> 6;
  bf16* sr = s + (long long)blockIdx.x * 4096;
  f32x4 f[4];
  float mx = -3.0e38f;
#pragma unroll
  for (int k = 0; k < 4; ++k) {
    const u16x4 raw = *(const u16x4*)(sr + (k * 256 + tid) * 4);
#pragma unroll
    for (int e = 0; e < 4; ++e) {
      f[k][e] = bf_bits2f(raw[e]);
      mx = fmaxf(mx, f[k][e]);
    }
  }
#pragma unroll
  for (int off = 32; off > 0; off >>= 1) mx = fmaxf(mx, __shfl_xor(mx, off));
  if (lane == 0) red[wid] = mx;
  __syncthreads();
  mx = fmaxf(fmaxf(red[0], red[1]), fmaxf(red[2], red[3]));
  __syncthreads();
  float sum = 0.f;
#pragma unroll
  for (int k = 0; k < 4; ++k)
#pragma unroll
    for (int e = 0; e < 4; ++e) {
      f[k][e] = __expf(f[k][e] - mx);
      sum += f[k][e];
    }
#pragma unroll
  for (int off = 32; off > 0; off >>= 1) sum += __shfl_xor(sum, off);
  if (lane == 0) red[wid] = sum;
  __syncthreads();
  const float inv = 1.0f / (red[0] + red[1] + red[2] + red[3]);
#pragma unroll
  for (int k = 0; k < 4; ++k) {
    u16x4 w;
#pragma unroll
    for (int e = 0; e < 4; ++e) w[e] = f2bf_bits(f[k][e] * inv);
    *(u16x4*)(sr + (k * 256 + tid) * 4) = w;
  }
}

// ---------------- merged prep: folds + tables + all fp32->bf16 casts ----------------
__global__ __launch_bounds__(256) void fold_all(
    const float* __restrict__ w, const float* __restrict__ b,
    const float* __restrict__ op_w, const float* __restrict__ exc,
    const float* __restrict__ ft_w, const float* __restrict__ x, bf16* __restrict__ weff,
    bf16* __restrict__ wvT, float* __restrict__ beff, float* __restrict__ cost,
    float* __restrict__ sint, float* __restrict__ lcos, float* __restrict__ lsin,
    bf16* __restrict__ ftw_b, bf16* __restrict__ opw_b, bf16* __restrict__ x_b) {
  __shared__ float tile[32][33];
  __shared__ float red[4];
  const int blk = blockIdx.x;
  const int tid = threadIdx.x;
  if (blk < 4096) {
    const int i = blk * 256 + tid;
    const int o = i >> 10, j = i & 1023;
    const int so = (o < 512) ? o : o + 512;
    const float* wr = w + (long long)so * 3072;
    weff[i] = __float2bfloat16(wr[j] + wr[1024 + j] + wr[2048 + j]);
    if (j == 0) beff[o] = b[so];
  } else if (blk < 5120) {
    const int tb = blk - 4096;
    const int t0 = (tb & 31) * 32, j0 = (tb >> 5) * 32;
    const int tx = tid & 31, ty = tid >> 5;
#pragma unroll
    for (int k = 0; k < 4; ++k) {
      const int t = t0 + ty + k * 8;
      const float* wr = w + (long long)(2048 + t) * 3072 + j0 + tx;
      tile[ty + k * 8][tx] = wr[0] + wr[1024] + wr[2048];
    }
    __syncthreads();
#pragma unroll
    for (int k = 0; k < 4; ++k) {
      const int r = ty + k * 8;
      wvT[(long long)(j0 + r) * 1024 + t0 + tx] = __float2bfloat16(tile[tx][r]);
    }
  } else if (blk < 6144) {
    const int o = blk - 5120;
    const int lane = tid & 63, wid = tid >> 6;
    float s = 0.f;
#pragma unroll
    for (int k = 0; k < 4; ++k) {
      const int t = tid + k * 256;
      s += op_w[(long long)o * 1024 + t] * b[2048 + t];
    }
#pragma unroll
    for (int off = 32; off > 0; off >>= 1) s += __shfl_xor(s, off);
    if (lane == 0) red[wid] = s;
    __syncthreads();
    if (tid == 0) beff[1024 + o] = red[0] + red[1] + red[2] + red[3];
  } else if (blk == 6144) {
    const double step = 6.283185307179586 / 1023.0;
#pragma unroll
    for (int k = 0; k < 4; ++k) {
      const int i = tid + k * 256;
      const float a = (float)((double)i * step);
      cost[i] = cosf(a);
      sint[i] = sinf(a);
    }
#pragma unroll
    for (int k = 0; k < 2; ++k) {
      const int i = tid + k * 256;
      const float el = ((float)i / 511.0f) * TWO_PI_F;
      const float m = fmodf(el, TWO_PI_F);
      int li = (int)((m / TWO_PI_F) * 1024.0f);
      li = min(max(li, 0), 1023);
      const float a = (float)((double)li * step);
      lcos[i] = cosf(a) * exc[0];
      lsin[i] = sinf(a) * exc[0];
    }
  } else if (blk < 6657) {
    const long long q = (long long)(blk - 6145) * 256 + tid;
    const f32x4 f = *(const f32x4*)(ft_w + q * 4);
    u16x4 wv;
#pragma unroll
    for (int e = 0; e < 4; ++e) wv[e] = f2bf_bits(f[e]);
    *(u16x4*)((unsigned short*)ftw_b + q * 4) = wv;
  } else if (blk < 7681) {
    const long long q = (long long)(blk - 6657) * 256 + tid;
    const f32x4 f = *(const f32x4*)(op_w + q * 4);
    u16x4 wv;
#pragma unroll
    for (int e = 0; e < 4; ++e) wv[e] = f2bf_bits(f[e]);
    *(u16x4*)((unsigned short*)opw_b + q * 4) = wv;
  } else {
    const long long q0 = (long long)(blk - 7681) * 256 + tid;
#pragma unroll
    for (int t = 0; t < 4; ++t) {
      const long long q = q0 + (long long)t * 524288;
      const f32x4 f = *(const f32x4*)(x + q * 4);
      u16x4 wv;
#pragma unroll
      for (int e = 0; e < 4; ++e) wv[e] = f2bf_bits(f[e]);
      *(u16x4*)((unsigned short*)x_b + q * 4) = wv;
    }
  }
}

extern "C" void kernel_launch(void* const* d_in, const int* in_sizes, int n_in, void* d_out,
                              int out_size, void* d_ws, size_t ws_size, hipStream_t stream) {
  const float* x = (const float*)d_in[0];
  const float* ft_w = (const float*)d_in[1];
  const float* ft_b = (const float*)d_in[2];
  const float* ln_g = (const float*)d_in[3];
  const float* ln_b = (const float*)d_in[4];
  const float* exc = (const float*)d_in[5];
  const float* qkv_w = (const float*)d_in[6];
  const float* qkv_b = (const float*)d_in[7];
  const float* op_w = (const float*)d_in[8];
  const float* op_b = (const float*)d_in[9];

  char* ws = (char*)d_ws;
  const size_t MB = 1024ull * 1024ull;
  bf16* ftw_b = (bf16*)(ws + 0);                // 1 MB
  bf16* weff = (bf16*)(ws + 1 * MB);            // 4 MB (q,k rows 0:1024; W_v2 1024:2048)
  bf16* opw_b = (bf16*)(ws + 5 * MB);           // 2 MB
  bf16* wvT = (bf16*)(ws + 7 * MB);             // 2 MB
  float* beff = (float*)(ws + 9 * MB);          // 8 KB
  float* cost = (float*)(ws + 9 * MB + 8192);
  float* sint = (float*)(ws + 9 * MB + 12288);
  float* lcos = (float*)(ws + 9 * MB + 16384);
  float* lsin = (float*)(ws + 9 * MB + 18432);
  bf16* v2T = (bf16*)(ws + 10 * MB);            // 32 MB (4 x 1024 x 4096)
  bf16* qk = (bf16*)(ws + 42 * MB);             // 32 MB (16384 x [q|k])
  bf16* x_b = (bf16*)(ws + 74 * MB);            // 16 MB, dead after stage A
  bf16* gbuf = (bf16*)(ws + 90 * MB);           // 32 MB, dead after LN
  bf16* ubuf = (bf16*)(ws + 122 * MB);          // 32 MB, dead after qk/v2 GEMMs
  bf16* sc = (bf16*)(ws + 74 * MB);             // scores: 128 MB (big) / 64 MB (pair)
  float* part0 = (float*)(ws + 138 * MB);       // 16 MB (fallback only)
  float* part1 = (float*)(ws + 154 * MB);       // 16 MB (fallback only)

  const bool big = ws_size >= 204 * MB;  // 4-batch sc fits (74 + 128 = 202 MB)

  fold_all<<<9729, 256, 0, stream>>>(qkv_w, qkv_b, op_w, exc, ft_w, x, weff, wvT, beff, cost,
                                     sint, lcos, lsin, ftw_b, opw_b, x_b);

  // W_v2 = op_w @ W_v -> weff rows 1024:2048
  gemm128<0, 1><<<dim3(8, 8), 256, 0, stream>>>(opw_b, wvT, weff + 1024 * 1024, nullptr,
                                                nullptr, 1024, 1024, 1024, 1024, 1.0f, 0, 0,
                                                0, nullptr, nullptr);
  // stage A: g = gelu(x @ ft_w^T + ft_b)
  gemm128<1, 1><<<dim3(8, 128), 256, 0, stream>>>(x_b, ftw_b, gbuf, nullptr, ft_b, 512, 512,
                                                  512, 1024, 1.0f, 0, 0, 0, nullptr, nullptr);
  // LN + phase -> u
  ln_phase_kernel<<<16384, 256, 0, stream>>>(gbuf, ubuf, ln_g, ln_b, lcos, lsin, cost, sint);
  // qk = u @ weff[0:1024]^T + beff  (packed bf16 stores)
  gemm128<0, 1><<<dim3(8, 128), 256, 0, stream>>>(ubuf, weff, qk, nullptr, beff, 1024, 1024,
                                                  1024, 1024, 1.0f, 0, 0, 0, nullptr, nullptr);
  // v2T = (u @ weff[1024:2048]^T + beff2) stored transposed per batch (LDS round-trip)
  gemm128<4, 0><<<dim3(8, 128), 256, 0, stream>>>(ubuf, weff + 1024 * 1024, nullptr, v2T,
                                                  beff + 1024, 1024, 1024, 1024, 0, 1.0f, 0,
                                                  0, 0, nullptr, nullptr);

  float* out0 = (float*)d_out;
  float* out1 = out0 + 8388608LL;
  if (big) {
    // all 4 batches in one pass: S -> softmax -> out = P @ V2 + op_b (full K)
    gemm128<2, 1><<<dim3(32, 32, 4), 256, 0, stream>>>(
        qk, qk + 512, sc, nullptr, nullptr, 512, 1024, 1024, 4096, 0.04419417382415922f,
        4096LL * 1024, 4096LL * 1024, 4096LL * 4096, nullptr, nullptr);
    softmax_kernel<<<16384, 256, 0, stream>>>(sc);
    gemm128<3, 1><<<dim3(8, 32, 4), 256, 0, stream>>>(
        sc, v2T, out0, out1, op_b, 4096, 4096, 4096, 0, 1.0f, 4096LL * 4096, 1024LL * 4096,
        0, nullptr, nullptr);
  } else {
    for (int p = 0; p < 2; ++p) {
      const bf16* qbase = qk + (long long)(2 * p) * 4096 * 1024;
      gemm128<2, 1><<<dim3(32, 32, 2), 256, 0, stream>>>(
          qbase, qbase + 512, sc, nullptr, nullptr, 512, 1024, 1024, 4096,
          0.04419417382415922f, 4096LL * 1024, 4096LL * 1024, 4096LL * 4096, nullptr,
          nullptr);
      softmax_kernel<<<8192, 256, 0, stream>>>(sc);
      gemm128<5, 1><<<dim3(8, 32, 4), 256, 0, stream>>>(
          sc, v2T + (long long)(2 * p) * 1024 * 4096, out0, out1, op_b, 2048, 4096, 4096, 0,
          1.0f, 4096LL * 4096, 1024LL * 4096, (long long)(2 * p) * 4096, part0, part1);
      combine_kernel<<<8192, 256, 0, stream>>>(part0, part1,
                                               out0 + (long long)(2 * p) * 4096 * 512,
                                               out1 + (long long)(2 * p) * 4096 * 512);
    }
  }
  (void)in_sizes;
  (void)n_in;
  (void)out_size;
}